// Round 5
// baseline (68.169 us; speedup 1.0000x reference)
//
#include <hip/hip_runtime.h>
#include <climits>
#include <cmath>

namespace {

constexpr int kHeads = 5;
constexpr int kA = 9;
constexpr int kWH = 40000;             // 200*200
constexpr int kG = 20;
constexpr int kN = kHeads * kA * kWH;  // 1,800,000
constexpr int kBlk = 256;
constexpr int kQuads = kWH / 4;        // 10000 quads per panel
constexpr int kBPP = (kQuads + kBlk - 1) / kBlk;   // 40 blocks per panel
constexpr int kPanels = kHeads * kA;   // 45
constexpr int kBlocks = kPanels * kBPP;            // 1800
constexpr int kWaves = kBlk / 64;
constexpr int kFBlk = 1024;

// Predicates, shared by main and the final winner-correction (MUST match):
//   iou <  0.3  <=>  uni<=0  ||  inter - 0.3*uni < 0
//   iou >= 0.7  <=>  uni>0   &&  inter - 0.7*uni >= 0
//   iou >  0    <=>  uni>0   &&  inter > 0        (exact)
__device__ __forceinline__ void iou_preds(
    float bx1, float by1, float bx2, float by2, float area_b,
    float gx1, float gy1, float gx2, float gy2, float area_g,
    bool& lt03, bool& ge07, bool& pos)
{
    const float iw = fmaxf(fminf(bx2, gx2) - fmaxf(bx1, gx1), 0.0f);
    const float ih = fmaxf(fminf(by2, gy2) - fmaxf(by1, gy1), 0.0f);
    const float inter = iw * ih;
    const float uni = area_b + area_g - inter;
    const bool unipos = uni > 0.0f;
    lt03 = !unipos || (fmaf(-0.3f, uni, inter) < 0.0f);
    ge07 = unipos && (fmaf(-0.7f, uni, inter) >= 0.0f);
    pos  = unipos && (inter > 0.0f);
}

__global__ __launch_bounds__(kBlk) void rpn_main(
    const float* __restrict__ cls,
    const float* __restrict__ reg,
    const float* __restrict__ gt,
    float* __restrict__ psum,
    int* __restrict__ pcnt,
    int* __restrict__ pminn,
    int* __restrict__ pwin)
{
    __shared__ float4 s_gt[kG];
    __shared__ float s_ag[kG];
    __shared__ int s_wwin[kWaves][kG];

    const int tid = threadIdx.x;
    if (tid < kG) {
        const float4 g = ((const float4*)gt)[tid];
        s_gt[tid] = g;
        s_ag[tid] = (g.z - g.x) * (g.w - g.y);
    }
    __syncthreads();

    // panel-major decomposition: a wave never straddles an (head,a) panel,
    // so flat index n is strictly increasing with (lane, i).
    const int p = blockIdx.x / kBPP;
    const int b = blockIdx.x - p * kBPP;
    const int head = p / kA;
    const int a = p - head * kA;
    const int q = b * kBlk + tid;
    const bool valid = q < kQuads;
    const int qc = valid ? q : (kQuads - 1);
    const int wh = qc * 4;
    const int lane = tid & 63;
    const int wv = tid >> 6;

    // 4 anchors per thread: wh, wh+1, wh+2, wh+3 (contiguous, 16B-aligned)
    const size_t rbase = (size_t)(head * (kA * 4) + a * 4) * kWH + wh;
    const float4 c0 = *(const float4*)(reg + rbase);                     // x1
    const float4 c1 = *(const float4*)(reg + rbase + (size_t)kWH);       // y1
    const float4 c2 = *(const float4*)(reg + rbase + 2 * (size_t)kWH);   // x2
    const float4 c3 = *(const float4*)(reg + rbase + 3 * (size_t)kWH);   // y2

    const float bx1[4] = { c0.x, c0.y, c0.z, c0.w };
    const float by1[4] = { c1.x, c1.y, c1.z, c1.w };
    const float bx2[4] = { c2.x, c2.y, c2.z, c2.w };
    const float by2[4] = { c3.x, c3.y, c3.z, c3.w };
    float areab[4];
    #pragma unroll
    for (int i = 0; i < 4; ++i)
        areab[i] = (bx2[i] - bx1[i]) * (by2[i] - by1[i]);

    const int n0 = (head * kWH + wh) * kA + a;   // anchor i: n0 + i*kA

    bool found[4] = { false, false, false, false };
    bool allw[4]  = { true, true, true, true };

    #pragma unroll
    for (int j = 0; j < kG; ++j) {
        const float4 g = s_gt[j];
        const float ag = s_ag[j];
        unsigned anyc = 0u;
        #pragma unroll
        for (int i = 0; i < 4; ++i) {
            bool lt03, ge07, pos;
            iou_preds(bx1[i], by1[i], bx2[i], by2[i], areab[i],
                      g.x, g.y, g.z, g.w, ag, lt03, ge07, pos);
            const bool reach = !found[i];
            allw[i] = allw[i] && (!reach || lt03);
            anyc |= (reach && pos) ? (1u << i) : 0u;
            found[i] = found[i] || ge07;
        }
        if (!valid) anyc = 0u;
        // per-gt per-wave winner: highest candidate lane holds max n;
        // within that lane, the highest candidate i holds its max n.
        const unsigned long long m = __ballot(anyc != 0u);
        const int hi = (m != 0ull) ? (63 - __clzll(m)) : 0;
        if (lane == hi) {
            const int best = 31 - __clz((int)(anyc | 1u));
            s_wwin[wv][j] = (m != 0ull) ? (n0 + best * kA) : -1;
        }
    }

    const size_t tbase = (size_t)(head * kA + a) * kWH + wh;
    const float4 pv = *(const float4*)(cls + tbase);
    const float pr[4] = { pv.x, pv.y, pv.z, pv.w };

    float bce = 0.0f;
    int kept = 0;
    int my_n = INT_MAX;
    #pragma unroll
    for (int i = 0; i < 4; ++i) {
        const bool k_i = valid && (found[i] || allw[i]);
        const float qv = found[i] ? pr[i] : (1.0f - pr[i]);
        bce += k_i ? (-__logf(qv)) : 0.0f;
        kept += k_i ? 1 : 0;
        my_n = min(my_n, k_i ? (n0 + i * kA) : INT_MAX);
    }

    // wave(64) reduction of sum/cnt/min
    for (int off = 32; off > 0; off >>= 1) {
        bce += __shfl_down(bce, off);
        kept += __shfl_down(kept, off);
        const int o = __shfl_down(my_n, off);
        my_n = min(my_n, o);
    }

    __shared__ float w_sum[kWaves];
    __shared__ int w_cnt[kWaves];
    __shared__ int w_min[kWaves];
    if ((tid & 63) == 0) {
        w_sum[wv] = bce; w_cnt[wv] = kept; w_min[wv] = my_n;
    }
    __syncthreads();

    if (tid == 0) {
        float s = 0.0f; int c = 0; int mn = INT_MAX;
        #pragma unroll
        for (int w = 0; w < kWaves; ++w) {
            s += w_sum[w]; c += w_cnt[w]; mn = min(mn, w_min[w]);
        }
        psum[blockIdx.x] = s;
        pcnt[blockIdx.x] = c;
        pminn[blockIdx.x] = mn;
    }
    if (tid < kG) {
        int v = -1;
        #pragma unroll
        for (int w = 0; w < kWaves; ++w) v = max(v, s_wwin[w][tid]);
        pwin[blockIdx.x * kG + tid] = v;
    }
}

__global__ __launch_bounds__(kFBlk) void rpn_final(
    const float* __restrict__ cls,
    const float* __restrict__ reg,
    const float* __restrict__ gt,
    const float* __restrict__ psum,
    const int* __restrict__ pcnt,
    const int* __restrict__ pminn,
    const int* __restrict__ pwin,
    float* __restrict__ out)
{
    const int tid = threadIdx.x;
    constexpr int kFWaves = kFBlk / 64;

    // deterministic strided reduction over block partials
    double s = 0.0;
    int c = 0;
    int mn = INT_MAX;
    int wmax[kG];
    #pragma unroll
    for (int j = 0; j < kG; ++j) wmax[j] = -1;

    for (int b = tid; b < kBlocks; b += kFBlk) {
        s += (double)psum[b];
        c += pcnt[b];
        mn = min(mn, pminn[b]);
        const int* pw = pwin + (size_t)b * kG;
        #pragma unroll
        for (int j = 0; j < kG; ++j) wmax[j] = max(wmax[j], pw[j]);
    }

    for (int off = 32; off > 0; off >>= 1) {
        s += __shfl_down(s, off);
        c += __shfl_down(c, off);
        const int o = __shfl_down(mn, off);
        mn = min(mn, o);
        #pragma unroll
        for (int j = 0; j < kG; ++j) {
            const int w = __shfl_down(wmax[j], off);
            wmax[j] = max(wmax[j], w);
        }
    }

    __shared__ double sd[kFWaves];
    __shared__ int scn[kFWaves], smn[kFWaves], swx[kFWaves][kG];
    if ((tid & 63) == 0) {
        const int w = tid >> 6;
        sd[w] = s; scn[w] = c; smn[w] = mn;
        #pragma unroll
        for (int j = 0; j < kG; ++j) swx[w][j] = wmax[j];
    }
    __syncthreads();

    __shared__ double sh_sum;
    __shared__ int sh_cnt, sh_mn;
    __shared__ int sh_wn[kG];
    if (tid == 0) {
        double S = 0.0; int C = 0; int M = INT_MAX;
        #pragma unroll
        for (int w = 0; w < kFWaves; ++w) {
            S += sd[w]; C += scn[w]; M = min(M, smn[w]);
        }
        sh_sum = S; sh_cnt = C; sh_mn = M;
        #pragma unroll
        for (int j = 0; j < kG; ++j) {
            int v = -1;
            for (int w = 0; w < kFWaves; ++w) v = max(v, swx[w][j]);
            sh_wn[j] = (v < 0) ? 0 : v;   // default anchor 0
        }
    }
    __syncthreads();

    // winner corrections: labels.at[winner].set(1.0) after zeroing
    double dsum = 0.0;
    int dcnt = 0;
    int wmin = INT_MAX;
    if (tid < kG) {
        const int n = sh_wn[tid];
        wmin = n;   // every winner becomes kept -> counts toward first_idx
        bool dup = false;
        for (int g2 = 0; g2 < tid; ++g2) dup |= (sh_wn[g2] == n);
        if (!dup) {
            // recompute this anchor's base label (same predicates as rpn_main!)
            const int a = n % kA;
            const int r = n / kA;
            const int wh = r % kWH;
            const int head = r / kWH;
            const float* rb = reg + (size_t)(head * (kA * 4) + a * 4) * kWH + wh;
            const float bx1 = rb[0];
            const float by1 = rb[kWH];
            const float bx2 = rb[2 * kWH];
            const float by2 = rb[3 * kWH];
            const float area_b = (bx2 - bx1) * (by2 - by1);
            bool allwrong = true; bool found = false;
            for (int j = 0; j < kG; ++j) {
                bool lt03, ge07, pos;
                iou_preds(bx1, by1, bx2, by2, area_b,
                          gt[4 * j + 0], gt[4 * j + 1], gt[4 * j + 2], gt[4 * j + 3],
                          (gt[4 * j + 2] - gt[4 * j + 0]) * (gt[4 * j + 3] - gt[4 * j + 1]),
                          lt03, ge07, pos);
                const bool reach = !found;
                allwrong = allwrong && (!reach || lt03);
                found = found || ge07;
            }
            if (!found) {
                const float p = cls[(size_t)(head * kA + a) * kWH + wh];
                if (allwrong) {
                    // base label 0 (kept): swap -log(1-p) for -log(p)
                    dsum = (double)(-__logf(p)) + (double)__logf(1.0f - p);
                } else {
                    // base label -1 (not kept): becomes kept with label 1
                    dsum = (double)(-__logf(p));
                    dcnt = 1;
                }
            }
        }
    }
    for (int off = 32; off > 0; off >>= 1) {
        dsum += __shfl_down(dsum, off);
        dcnt += __shfl_down(dcnt, off);
        const int o = __shfl_down(wmin, off);
        wmin = min(wmin, o);
    }

    if (tid == 0) {
        const double total_sum = sh_sum + dsum;
        const int total_cnt = sh_cnt + dcnt;
        const int firstk = min(sh_mn, wmin);

        const float cls_loss = (float)total_sum / (float)total_cnt;

        // reg loss: first kept anchor's box vs all gts, smooth L1, mean
        const int a = firstk % kA;
        const int r = firstk / kA;
        const int wh = r % kWH;
        const int head = r / kWH;
        const float* rb = reg + (size_t)(head * (kA * 4) + a * 4) * kWH + wh;
        const float b0[4] = { rb[0], rb[kWH], rb[2 * kWH], rb[3 * kWH] };
        float rl = 0.0f;
        for (int g = 0; g < kG; ++g) {
            #pragma unroll
            for (int k = 0; k < 4; ++k) {
                const float d = fabsf(b0[k] - gt[4 * g + k]);
                rl += (d < 1.0f) ? (0.5f * d * d) : (d - 0.5f);
            }
        }
        rl /= (float)(kG * 4);

        out[0] = cls_loss / 256.0f + rl / 2400.0f;
    }
}

}  // namespace

extern "C" void kernel_launch(void* const* d_in, const int* in_sizes, int n_in,
                              void* d_out, int out_size, void* d_ws, size_t ws_size,
                              hipStream_t stream) {
    const float* cls = (const float*)d_in[0];
    const float* reg = (const float*)d_in[1];
    const float* gt  = (const float*)d_in[2];
    float* out = (float*)d_out;

    float* psum = (float*)d_ws;
    int* pcnt = (int*)(psum + kBlocks);
    int* pminn = pcnt + kBlocks;
    int* pwin = pminn + kBlocks;   // kBlocks * kG ints

    rpn_main<<<kBlocks, kBlk, 0, stream>>>(cls, reg, gt, psum, pcnt, pminn, pwin);
    rpn_final<<<1, kFBlk, 0, stream>>>(cls, reg, gt, psum, pcnt, pminn, pwin, out);
}

// Round 6
// 62.058 us; speedup vs baseline: 1.0985x; 1.0985x over previous
//
#include <hip/hip_runtime.h>
#include <climits>
#include <cmath>

namespace {

constexpr int kHeads = 5;
constexpr int kA = 9;
constexpr int kWH = 40000;             // 200*200
constexpr int kG = 20;
constexpr int kN = kHeads * kA * kWH;  // 1,800,000
constexpr int kBlk = 256;
constexpr int kQuads = kWH / 4;        // 10000 quads per panel
constexpr int kBPP = (kQuads + kBlk - 1) / kBlk;   // 40 blocks per panel
constexpr int kPanels = kHeads * kA;   // 45
constexpr int kBlocks = kPanels * kBPP;            // 1800
constexpr int kWaves = kBlk / 64;
constexpr int kFBlk = 1024;

// Predicates (final winner-correction MUST match rpn_main's mask forms):
//   iou <  0.3  <=>  uni<=0  ||  inter - 0.3*uni < 0
//   iou >= 0.7  <=>  uni>0   &&  inter - 0.7*uni >= 0
//   iou >  0    <=>  uni>0   &&  inter > 0        (exact)
__device__ __forceinline__ void iou_preds(
    float bx1, float by1, float bx2, float by2, float area_b,
    float gx1, float gy1, float gx2, float gy2, float area_g,
    bool& lt03, bool& ge07, bool& pos)
{
    const float iw = fmaxf(fminf(bx2, gx2) - fmaxf(bx1, gx1), 0.0f);
    const float ih = fmaxf(fminf(by2, gy2) - fmaxf(by1, gy1), 0.0f);
    const float inter = iw * ih;
    const float uni = area_b + area_g - inter;
    const bool unipos = uni > 0.0f;
    lt03 = !unipos || (fmaf(-0.3f, uni, inter) < 0.0f);
    ge07 = unipos && (fmaf(-0.7f, uni, inter) >= 0.0f);
    pos  = unipos && (inter > 0.0f);
}

__global__ __launch_bounds__(kBlk) void rpn_main(
    const float* __restrict__ cls,
    const float* __restrict__ reg,
    const float* __restrict__ gt,
    float* __restrict__ psum,
    int* __restrict__ pcnt,
    int* __restrict__ pminn,
    int* __restrict__ pwin)
{
    __shared__ float4 s_gt[kG];
    __shared__ float s_ag[kG];
    __shared__ int s_wwin[kWaves][kG];

    const int tid = threadIdx.x;
    if (tid < kG) {
        const float4 g = ((const float4*)gt)[tid];
        s_gt[tid] = g;
        s_ag[tid] = (g.z - g.x) * (g.w - g.y);
    }
    __syncthreads();

    // panel-major decomposition: a wave never straddles an (head,a) panel,
    // so flat index n is strictly increasing with (lane, i).
    const int p = blockIdx.x / kBPP;
    const int b = blockIdx.x - p * kBPP;
    const int head = p / kA;
    const int a = p - head * kA;
    const int q = b * kBlk + tid;
    const bool valid = q < kQuads;
    const int qc = valid ? q : (kQuads - 1);
    const int wh = qc * 4;
    const int lane = tid & 63;
    const int wv = tid >> 6;

    // 4 anchors per thread: wh..wh+3 (contiguous, 16B-aligned)
    const size_t rbase = (size_t)(head * (kA * 4) + a * 4) * kWH + wh;
    const float4 c0 = *(const float4*)(reg + rbase);                     // x1
    const float4 c1 = *(const float4*)(reg + rbase + (size_t)kWH);       // y1
    const float4 c2 = *(const float4*)(reg + rbase + 2 * (size_t)kWH);   // x2
    const float4 c3 = *(const float4*)(reg + rbase + 3 * (size_t)kWH);   // y2
    const size_t tbase = (size_t)(head * kA + a) * kWH + wh;
    const float4 pv = *(const float4*)(cls + tbase);   // issued early

    const float bx1[4] = { c0.x, c0.y, c0.z, c0.w };
    const float by1[4] = { c1.x, c1.y, c1.z, c1.w };
    const float bx2[4] = { c2.x, c2.y, c2.z, c2.w };
    const float by2[4] = { c3.x, c3.y, c3.z, c3.w };
    float areab[4];
    #pragma unroll
    for (int i = 0; i < 4; ++i)
        areab[i] = (bx2[i] - bx1[i]) * (by2[i] - by1[i]);

    const int n0 = (head * kWH + wh) * kA + a;   // anchor i: n0 + i*kA

    // Pure-VALU mask accumulation: no cross-j deps, no SALU boolean algebra.
    unsigned ge07m[4] = { 0u, 0u, 0u, 0u };   // bit j: iou_j >= 0.7
    unsigned posm[4]  = { 0u, 0u, 0u, 0u };   // bit j: iou_j > 0
    unsigned allwI[4] = { 1u, 1u, 1u, 1u };   // 1 while all j so far have iou<0.3

    #pragma unroll
    for (int j = 0; j < kG; ++j) {
        const float4 g = s_gt[j];
        const float ag = s_ag[j];
        const unsigned bitj = 1u << j;
        #pragma unroll
        for (int i = 0; i < 4; ++i) {
            const float iw = fmaxf(fminf(bx2[i], g.z) - fmaxf(bx1[i], g.x), 0.0f);
            const float ih = fmaxf(fminf(by2[i], g.w) - fmaxf(by1[i], g.y), 0.0f);
            const float inter = iw * ih;
            const float uni = areab[i] + ag - inter;
            const bool unipos = uni > 0.0f;          // one v_cmp, reused via cndmask
            const float t7 = unipos ? fmaf(-0.7f, uni, inter) : -1.0f;
            const float t3 = unipos ? fmaf(-0.3f, uni, inter) : -1.0f;
            const float tp = unipos ? inter : -1.0f;
            ge07m[i] |= (t7 >= 0.0f) ? bitj : 0u;    // ge07 = unipos && t7>=0
            allwI[i]  = (t3 >= 0.0f) ? 0u : allwI[i];// lt03 = !(unipos && t3>=0)
            posm[i]  |= (tp >  0.0f) ? bitj : 0u;    // pos  = unipos && inter>0
        }
    }

    // reach mask from first ge07 bit: bits 0..ff inclusive (all if none)
    unsigned candm[4];
    #pragma unroll
    for (int i = 0; i < 4; ++i) {
        const unsigned gm = ge07m[i];
        const unsigned lb = gm & (unsigned)(-(int)gm);
        const unsigned reachm = gm ? (lb | (lb - 1u)) : ((1u << kG) - 1u);
        candm[i] = valid ? (posm[i] & reachm) : 0u;
    }

    const float pr[4] = { pv.x, pv.y, pv.z, pv.w };
    float bce = 0.0f;
    int kept = 0;
    int my_n = INT_MAX;
    #pragma unroll
    for (int i = 0; i < 4; ++i) {
        const bool found = ge07m[i] != 0u;
        const bool k_i = valid && (found || allwI[i] != 0u);
        const float qv = found ? pr[i] : (1.0f - pr[i]);
        bce += k_i ? (-__logf(qv)) : 0.0f;
        kept += k_i ? 1 : 0;
        my_n = min(my_n, k_i ? (n0 + i * kA) : INT_MAX);
    }

    // per-gt per-wave winner (out of the hot loop): highest lane, then highest i
    #pragma unroll
    for (int j = 0; j < kG; ++j) {
        const unsigned nib = ((candm[0] >> j) & 1u)
                           | (((candm[1] >> j) & 1u) << 1)
                           | (((candm[2] >> j) & 1u) << 2)
                           | (((candm[3] >> j) & 1u) << 3);
        const unsigned long long m = __ballot(nib != 0u);
        const int hi = (m != 0ull) ? (63 - __clzll(m)) : 0;
        if (lane == hi) {
            const int best = 31 - __clz((int)(nib | 1u));
            s_wwin[wv][j] = (m != 0ull) ? (n0 + best * kA) : -1;
        }
    }

    // wave(64) reduction of sum/cnt/min
    for (int off = 32; off > 0; off >>= 1) {
        bce += __shfl_down(bce, off);
        kept += __shfl_down(kept, off);
        const int o = __shfl_down(my_n, off);
        my_n = min(my_n, o);
    }

    __shared__ float w_sum[kWaves];
    __shared__ int w_cnt[kWaves];
    __shared__ int w_min[kWaves];
    if ((tid & 63) == 0) {
        w_sum[wv] = bce; w_cnt[wv] = kept; w_min[wv] = my_n;
    }
    __syncthreads();

    if (tid == 0) {
        float s = 0.0f; int c = 0; int mn = INT_MAX;
        #pragma unroll
        for (int w = 0; w < kWaves; ++w) {
            s += w_sum[w]; c += w_cnt[w]; mn = min(mn, w_min[w]);
        }
        psum[blockIdx.x] = s;
        pcnt[blockIdx.x] = c;
        pminn[blockIdx.x] = mn;
    }
    if (tid < kG) {
        int v = -1;
        #pragma unroll
        for (int w = 0; w < kWaves; ++w) v = max(v, s_wwin[w][tid]);
        pwin[blockIdx.x * kG + tid] = v;
    }
}

__global__ __launch_bounds__(kFBlk) void rpn_final(
    const float* __restrict__ cls,
    const float* __restrict__ reg,
    const float* __restrict__ gt,
    const float* __restrict__ psum,
    const int* __restrict__ pcnt,
    const int* __restrict__ pminn,
    const int* __restrict__ pwin,
    float* __restrict__ out)
{
    const int tid = threadIdx.x;
    constexpr int kFWaves = kFBlk / 64;

    // deterministic strided reduction over block partials
    double s = 0.0;
    int c = 0;
    int mn = INT_MAX;
    int wmax[kG];
    #pragma unroll
    for (int j = 0; j < kG; ++j) wmax[j] = -1;

    for (int b = tid; b < kBlocks; b += kFBlk) {
        s += (double)psum[b];
        c += pcnt[b];
        mn = min(mn, pminn[b]);
        const int* pw = pwin + (size_t)b * kG;
        #pragma unroll
        for (int j = 0; j < kG; ++j) wmax[j] = max(wmax[j], pw[j]);
    }

    for (int off = 32; off > 0; off >>= 1) {
        s += __shfl_down(s, off);
        c += __shfl_down(c, off);
        const int o = __shfl_down(mn, off);
        mn = min(mn, o);
        #pragma unroll
        for (int j = 0; j < kG; ++j) {
            const int w = __shfl_down(wmax[j], off);
            wmax[j] = max(wmax[j], w);
        }
    }

    __shared__ double sd[kFWaves];
    __shared__ int scn[kFWaves], smn[kFWaves], swx[kFWaves][kG];
    if ((tid & 63) == 0) {
        const int w = tid >> 6;
        sd[w] = s; scn[w] = c; smn[w] = mn;
        #pragma unroll
        for (int j = 0; j < kG; ++j) swx[w][j] = wmax[j];
    }
    __syncthreads();

    __shared__ double sh_sum;
    __shared__ int sh_cnt, sh_mn;
    __shared__ int sh_wn[kG];
    if (tid == 0) {
        double S = 0.0; int C = 0; int M = INT_MAX;
        #pragma unroll
        for (int w = 0; w < kFWaves; ++w) {
            S += sd[w]; C += scn[w]; M = min(M, smn[w]);
        }
        sh_sum = S; sh_cnt = C; sh_mn = M;
        #pragma unroll
        for (int j = 0; j < kG; ++j) {
            int v = -1;
            for (int w = 0; w < kFWaves; ++w) v = max(v, swx[w][j]);
            sh_wn[j] = (v < 0) ? 0 : v;   // default anchor 0
        }
    }
    __syncthreads();

    // winner corrections: labels.at[winner].set(1.0) after zeroing
    double dsum = 0.0;
    int dcnt = 0;
    int wmin = INT_MAX;
    if (tid < kG) {
        const int n = sh_wn[tid];
        wmin = n;   // every winner becomes kept -> counts toward first_idx
        bool dup = false;
        for (int g2 = 0; g2 < tid; ++g2) dup |= (sh_wn[g2] == n);
        if (!dup) {
            // recompute this anchor's base label (same predicates as rpn_main!)
            const int a = n % kA;
            const int r = n / kA;
            const int wh = r % kWH;
            const int head = r / kWH;
            const float* rb = reg + (size_t)(head * (kA * 4) + a * 4) * kWH + wh;
            const float bx1 = rb[0];
            const float by1 = rb[kWH];
            const float bx2 = rb[2 * kWH];
            const float by2 = rb[3 * kWH];
            const float area_b = (bx2 - bx1) * (by2 - by1);
            bool allwrong = true; bool found = false;
            for (int j = 0; j < kG; ++j) {
                bool lt03, ge07, pos;
                iou_preds(bx1, by1, bx2, by2, area_b,
                          gt[4 * j + 0], gt[4 * j + 1], gt[4 * j + 2], gt[4 * j + 3],
                          (gt[4 * j + 2] - gt[4 * j + 0]) * (gt[4 * j + 3] - gt[4 * j + 1]),
                          lt03, ge07, pos);
                allwrong = allwrong && lt03;   // == reach-based form (proof in R6 notes)
                found = found || ge07;
            }
            if (!found) {
                const float p = cls[(size_t)(head * kA + a) * kWH + wh];
                if (allwrong) {
                    // base label 0 (kept): swap -log(1-p) for -log(p)
                    dsum = (double)(-__logf(p)) + (double)__logf(1.0f - p);
                } else {
                    // base label -1 (not kept): becomes kept with label 1
                    dsum = (double)(-__logf(p));
                    dcnt = 1;
                }
            }
        }
    }
    for (int off = 32; off > 0; off >>= 1) {
        dsum += __shfl_down(dsum, off);
        dcnt += __shfl_down(dcnt, off);
        const int o = __shfl_down(wmin, off);
        wmin = min(wmin, o);
    }

    if (tid == 0) {
        const double total_sum = sh_sum + dsum;
        const int total_cnt = sh_cnt + dcnt;
        const int firstk = min(sh_mn, wmin);

        const float cls_loss = (float)total_sum / (float)total_cnt;

        // reg loss: first kept anchor's box vs all gts, smooth L1, mean
        const int a = firstk % kA;
        const int r = firstk / kA;
        const int wh = r % kWH;
        const int head = r / kWH;
        const float* rb = reg + (size_t)(head * (kA * 4) + a * 4) * kWH + wh;
        const float b0[4] = { rb[0], rb[kWH], rb[2 * kWH], rb[3 * kWH] };
        float rl = 0.0f;
        for (int g = 0; g < kG; ++g) {
            #pragma unroll
            for (int k = 0; k < 4; ++k) {
                const float d = fabsf(b0[k] - gt[4 * g + k]);
                rl += (d < 1.0f) ? (0.5f * d * d) : (d - 0.5f);
            }
        }
        rl /= (float)(kG * 4);

        out[0] = cls_loss / 256.0f + rl / 2400.0f;
    }
}

}  // namespace

extern "C" void kernel_launch(void* const* d_in, const int* in_sizes, int n_in,
                              void* d_out, int out_size, void* d_ws, size_t ws_size,
                              hipStream_t stream) {
    const float* cls = (const float*)d_in[0];
    const float* reg = (const float*)d_in[1];
    const float* gt  = (const float*)d_in[2];
    float* out = (float*)d_out;

    float* psum = (float*)d_ws;
    int* pcnt = (int*)(psum + kBlocks);
    int* pminn = pcnt + kBlocks;
    int* pwin = pminn + kBlocks;   // kBlocks * kG ints

    rpn_main<<<kBlocks, kBlk, 0, stream>>>(cls, reg, gt, psum, pcnt, pminn, pwin);
    rpn_final<<<1, kFBlk, 0, stream>>>(cls, reg, gt, psum, pcnt, pminn, pwin, out);
}